// Round 7
// baseline (610.325 us; speedup 1.0000x reference)
//
#include <hip/hip_runtime.h>

typedef __attribute__((ext_vector_type(8))) short short8;
typedef __attribute__((ext_vector_type(4))) float floatx4;
typedef __attribute__((ext_vector_type(4))) unsigned uintx4;
typedef __attribute__((ext_vector_type(8))) _Float16 half8;

// ---- bf16 split helpers (round-to-nearest-even) ----
static __device__ __forceinline__ unsigned short f2bf(float f) {
    unsigned u = __float_as_uint(f);
    u += 0x7fff + ((u >> 16) & 1);
    return (unsigned short)(u >> 16);
}
static __device__ __forceinline__ float bf2f(unsigned short h) {
    return __uint_as_float((unsigned)h << 16);
}
static __device__ __forceinline__ unsigned packsplit(float f) {
    unsigned short hi = f2bf(f);
    unsigned short lo = f2bf(f - bf2f(hi));
    return ((unsigned)hi << 16) | lo;
}

// ---------------- CSR build ----------------
// degi/hist/hcur zeroed by one host-side hipMemsetAsync over a contiguous region.
// CSR contains ONLY the E real edges; self-loops are streamed in agg_kernel.

__global__ void count_kernel(const int* __restrict__ ei, int* degi, int E) {
    int e = blockIdx.x * 256 + threadIdx.x;
    if (e < E) atomicAdd(&degi[ei[E + e]], 1);   // col = dest
}

// per-block sums of deg + fused dinv + fused 64-bucket degree histogram
__global__ __launch_bounds__(256) void scan_bsum_kernel(const int* __restrict__ degi,
                                                        float* __restrict__ dinv,
                                                        int* bsum, int* hist, int n) {
    __shared__ int sh[64];
    int tid = threadIdx.x;
    if (tid < 64) sh[tid] = 0;
    __syncthreads();
    int i = blockIdx.x * 256 + tid;
    int d = (i < n) ? degi[i] : 0;
    if (i < n) {
        dinv[i] = rsqrtf((float)(d + 1));  // +1 self-loop for normalization
        atomicAdd(&sh[min(d, 63)], 1);
    }
    int v = d;                             // offsets count only real edges
    #pragma unroll
    for (int off = 32; off > 0; off >>= 1) v += __shfl_down(v, off);
    __shared__ int ws[4];
    if ((tid & 63) == 0) ws[tid >> 6] = v;
    __syncthreads();
    if (tid == 0) bsum[blockIdx.x] = ws[0] + ws[1] + ws[2] + ws[3];
    if (tid < 64 && sh[tid] > 0) atomicAdd(&hist[tid], sh[tid]);
}

// exclusive scan of the 64-bucket histogram -> bucket cursors (one wave)
__global__ void bucket_scan_kernel(const int* __restrict__ hist, int* hcur) {
    int l = threadIdx.x;        // 64 threads
    int v = hist[l];
    int x = v;
    #pragma unroll
    for (int off = 1; off < 64; off <<= 1) {
        int y = __shfl_up(x, off);
        if (l >= off) x += y;
    }
    hcur[l] = x - v;            // exclusive prefix
}

// scatter nodes into degree-sorted order (any within-bucket order is a valid permutation)
__global__ void order_kernel(const int* __restrict__ degi, int* hcur,
                             int* __restrict__ order, int n) {
    int j = blockIdx.x * 256 + threadIdx.x;
    if (j >= n) return;
    int b = min(degi[j], 63);
    int pos = atomicAdd(&hcur[b], 1);
    order[pos] = j;
}

__global__ __launch_bounds__(256) void scan_emit_kernel(const int* __restrict__ degi,
                                                        const int* __restrict__ bsum,
                                                        int* rp, int* cursor, int n, int nb) {
    int tid = threadIdx.x;
    int bid = blockIdx.x;
    int contrib = 0;
    for (int t = tid; t < bid; t += 256) contrib += bsum[t];
    int cr = contrib;
    #pragma unroll
    for (int off = 32; off > 0; off >>= 1) cr += __shfl_down(cr, off);
    __shared__ int wr[4];
    __shared__ int s_boff;
    if ((tid & 63) == 0) wr[tid >> 6] = cr;
    __syncthreads();
    if (tid == 0) s_boff = wr[0] + wr[1] + wr[2] + wr[3];
    __syncthreads();

    int i = bid * 256 + tid;
    int v = (i < n) ? degi[i] : 0;
    int lane = tid & 63, wid = tid >> 6;
    int x = v;
    #pragma unroll
    for (int off = 1; off < 64; off <<= 1) {
        int y = __shfl_up(x, off);
        if (lane >= off) x += y;
    }
    __shared__ int ws[4];
    if (lane == 63) ws[wid] = x;
    __syncthreads();
    if (tid == 0) { int a = 0; for (int j = 0; j < 4; ++j) { int t = ws[j]; ws[j] = a; a += t; } }
    __syncthreads();
    int excl = x - v + ws[wid] + s_boff;
    if (i < n) { rp[i] = excl; cursor[i] = excl; }
    if (i == n - 1) rp[n] = excl + v;
}

__global__ void fill_kernel(const int* __restrict__ ei, const float* __restrict__ dinv,
                            int* cursor, long long* __restrict__ csr, int E) {
    int e = blockIdx.x * 256 + threadIdx.x;
    if (e >= E) return;
    int r = ei[e], c = ei[E + e];
    int pos = atomicAdd(&cursor[c], 1);
    float wv = dinv[r] * dinv[c];
    long long packed = (long long)(unsigned int)r
                     | ((long long)(unsigned int)__float_as_int(wv) << 32);
    csr[pos] = packed;
}

// ---------------- weight packing: W[k][n] -> Wt_hi[n][k], Wt_lo[n][k] ----------------

__global__ void packw_kernel(const float* w0, const float* w1, const float* w2,
                             const float* w3, const float* w4, const float* w5,
                             unsigned short* __restrict__ hi, unsigned short* __restrict__ lo) {
    int l = blockIdx.y;
    const float* W = (l == 0) ? w0 : (l == 1) ? w1 : (l == 2) ? w2
                   : (l == 3) ? w3 : (l == 4) ? w4 : w5;
    int idx = blockIdx.x * 256 + threadIdx.x;
    int k = idx >> 7, nn = idx & 127;
    float v = W[k * 128 + nn];
    unsigned short h = f2bf(v);
    unsigned short ls = f2bf(v - bf2f(h));
    hi[l * 16384 + nn * 128 + k] = h;
    lo[l * 16384 + nn * 128 + k] = ls;
}

// ---------------- split-bf16 MFMA GEMM core ----------------
// A-input: hp packed split-bf16, chunked [8][node][16] (chunk = col/16).
// __launch_bounds__(512, 4): force 4 waves/EU = 16 waves/CU = 2 blocks/CU co-residency
// (VGPR cap 128). Without the hint the compiler may exceed 128 VGPR -> 1 block/CU ->
// 2 waves/SIMD, too few to hide the ds_read->MFMA chain.
// 3-MFMA split product (al*wl dropped, absmax-neutral per R5/R6).

#define WLDS_STRIDE 260

static __device__ __forceinline__ void stage_w(const unsigned short* __restrict__ Wth,
                                               const unsigned short* __restrict__ Wtl,
                                               unsigned short* Wlds, int tid) {
    #pragma unroll
    for (int it = 0; it < 8; ++it) {
        int c = it * 512 + tid;
        int row = c >> 5, piece = c & 31;
        const unsigned short* src = (piece < 16)
            ? (Wth + (size_t)row * 128 + piece * 8)
            : (Wtl + (size_t)row * 128 + (piece - 16) * 8);
        int dst = row * WLDS_STRIDE + ((piece < 16) ? piece * 8 : 128 + (piece - 16) * 8);
        *(short8*)&Wlds[dst] = *(const short8*)src;
    }
}

static __device__ __forceinline__ void unpack_u(uintx4 u0, uintx4 u1, short8& ah, short8& al) {
    #pragma unroll
    for (int j = 0; j < 4; ++j) {
        ah[j]     = (short)(u0[j] >> 16); al[j]     = (short)(u0[j] & 0xffff);
        ah[4 + j] = (short)(u1[j] >> 16); al[4 + j] = (short)(u1[j] & 0xffff);
    }
}

__global__ __launch_bounds__(512, 4) void gemm_kernel(const unsigned* __restrict__ Ap,
                                                      const unsigned short* __restrict__ Wth,
                                                      const unsigned short* __restrict__ Wtl,
                                                      void* __restrict__ C, int n, int outf) {
    __shared__ unsigned short Wlds[128 * WLDS_STRIDE];
    int tid = threadIdx.x;
    int wave = tid >> 6, lane = tid & 63;
    int m = lane & 15, quad = lane >> 4;
    int row0 = blockIdx.x * 128 + wave * 16;
    int arow = row0 + m; if (arow > n - 1) arow = n - 1;
    size_t n16 = (size_t)n * 16;
    size_t n32 = (size_t)n * 32;
    const unsigned* abase = Ap + (size_t)arow * 16 + (quad & 1) * 8;
    int chalf = quad >> 1;

    // prefetch ALL kc A-fragments before W staging
    uintx4 pa0[4], pa1[4];
    #pragma unroll
    for (int kc = 0; kc < 4; ++kc) {
        const unsigned* ap = abase + (size_t)(2 * kc + chalf) * n16;
        pa0[kc] = *(const uintx4*)ap;
        pa1[kc] = *(const uintx4*)(ap + 4);
    }

    stage_w(Wth, Wtl, Wlds, tid);

    floatx4 acc[8];
    #pragma unroll
    for (int ct = 0; ct < 8; ++ct) acc[ct] = (floatx4){0.f, 0.f, 0.f, 0.f};
    __syncthreads();

    #pragma unroll
    for (int kc = 0; kc < 4; ++kc) {
        short8 ah, al;
        unpack_u(pa0[kc], pa1[kc], ah, al);
        #pragma unroll
        for (int ct = 0; ct < 8; ++ct) {
            int base = (ct * 16 + m) * WLDS_STRIDE + kc * 32 + quad * 8;
            short8 wh = *(const short8*)&Wlds[base];
            short8 wl = *(const short8*)&Wlds[base + 128];
            acc[ct] = __builtin_amdgcn_mfma_f32_16x16x32_bf16(ah, wl, acc[ct], 0, 0, 0);
            acc[ct] = __builtin_amdgcn_mfma_f32_16x16x32_bf16(al, wh, acc[ct], 0, 0, 0);
            acc[ct] = __builtin_amdgcn_mfma_f32_16x16x32_bf16(ah, wh, acc[ct], 0, 0, 0);
        }
    }
    #pragma unroll
    for (int ct = 0; ct < 8; ++ct) {
        #pragma unroll
        for (int r = 0; r < 4; ++r) {
            int row = row0 + quad * 4 + r;
            if (row < n) {
                if (outf) {
                    ((float*)C)[(size_t)row * 128 + ct * 16 + m] = acc[ct][r];
                } else {
                    ((_Float16*)C)[(size_t)(ct >> 1) * n32 + (size_t)row * 32
                                   + (ct & 1) * 16 + m] = (_Float16)acc[ct][r];
                }
            }
        }
    }
}

// layer-0 variant: reads fp32 x (row-major input) directly; fp16-chunked out
__global__ __launch_bounds__(512, 4) void gemm0_kernel(const float* __restrict__ X,
                                                       const unsigned short* __restrict__ Wth,
                                                       const unsigned short* __restrict__ Wtl,
                                                       _Float16* __restrict__ C, int n) {
    __shared__ unsigned short Wlds[128 * WLDS_STRIDE];
    int tid = threadIdx.x;
    int wave = tid >> 6, lane = tid & 63;
    int m = lane & 15, quad = lane >> 4;
    int row0 = blockIdx.x * 128 + wave * 16;
    int arow = row0 + m; if (arow > n - 1) arow = n - 1;
    size_t n32 = (size_t)n * 32;
    const float* aptr = X + (size_t)arow * 128 + quad * 8;

    floatx4 pf0[4], pf1[4];
    #pragma unroll
    for (int kc = 0; kc < 4; ++kc) {
        pf0[kc] = *(const floatx4*)(aptr + kc * 32);
        pf1[kc] = *(const floatx4*)(aptr + kc * 32 + 4);
    }

    stage_w(Wth, Wtl, Wlds, tid);

    floatx4 acc[8];
    #pragma unroll
    for (int ct = 0; ct < 8; ++ct) acc[ct] = (floatx4){0.f, 0.f, 0.f, 0.f};
    __syncthreads();

    #pragma unroll
    for (int kc = 0; kc < 4; ++kc) {
        short8 ah, al;
        #pragma unroll
        for (int j = 0; j < 8; ++j) {
            float fv = (j < 4) ? pf0[kc][j] : pf1[kc][j - 4];
            unsigned short h = f2bf(fv);
            ah[j] = (short)h;
            al[j] = (short)f2bf(fv - bf2f(h));
        }
        #pragma unroll
        for (int ct = 0; ct < 8; ++ct) {
            int base = (ct * 16 + m) * WLDS_STRIDE + kc * 32 + quad * 8;
            short8 wh = *(const short8*)&Wlds[base];
            short8 wl = *(const short8*)&Wlds[base + 128];
            acc[ct] = __builtin_amdgcn_mfma_f32_16x16x32_bf16(ah, wl, acc[ct], 0, 0, 0);
            acc[ct] = __builtin_amdgcn_mfma_f32_16x16x32_bf16(al, wh, acc[ct], 0, 0, 0);
            acc[ct] = __builtin_amdgcn_mfma_f32_16x16x32_bf16(ah, wh, acc[ct], 0, 0, 0);
        }
    }
    #pragma unroll
    for (int ct = 0; ct < 8; ++ct) {
        #pragma unroll
        for (int r = 0; r < 4; ++r) {
            int row = row0 + quad * 4 + r;
            if (row < n)
                C[(size_t)(ct >> 1) * n32 + (size_t)row * 32 + (ct & 1) * 16 + m] =
                    (_Float16)acc[ct][r];
        }
    }
}

// ---------------- aggregation: fp16 gather, 4 chunks of 32 cols, XCD-pinned ----------------
// t layout: [4][node][32] fp16; blockIdx%8 = s: chunk = s&3, node-half = s>>2.
// DEGREE-SORTED processing order (j = order[idx]): a wave's 16 nodes have near-equal
// degree, so loop trips = max over groups ~= avg (was ~1.5x inflated by Poisson max).
// Per-node arithmetic identical (same csr segment, same order) -> bitwise-same output.

__global__ __launch_bounds__(256) void agg_kernel(const _Float16* __restrict__ t,
                                                  const float* __restrict__ bias,
                                                  const int* __restrict__ rp,
                                                  const long long* __restrict__ csr,
                                                  const float* __restrict__ dinv,
                                                  const int* __restrict__ order,
                                                  unsigned* __restrict__ hp, int n, int nh) {
    int s = blockIdx.x & 7;
    int chunk = s & 3;
    int half = s >> 2;
    int nb = blockIdx.x >> 3;
    int group = threadIdx.x >> 2;          // 64 nodes per block
    int lane4 = threadIdx.x & 3;
    int idx = half * nh + nb * 64 + group;
    int iend = half ? n : nh;
    if (idx >= iend) return;
    int j = order[idx];
    size_t n32 = (size_t)n * 32;
    const _Float16* tc = t + (size_t)chunk * n32;
    int c8 = lane4 * 8;                    // col offset within the 32-col chunk
    int p0 = rp[j], p1 = rp[j + 1];

    // self-loop: issued first (overlaps csr latency)
    float dj = dinv[j];
    float wsf = dj * dj;
    half8 vs = *(const half8*)&tc[(size_t)j * 32 + c8];

    float acc[8];
    #pragma unroll
    for (int k = 0; k < 8; ++k) acc[k] = wsf * (float)vs[k];

    for (int p = p0; p < p1; p += 8) {
        int lim = p1 - 1;
        long long e[8];
        #pragma unroll
        for (int i = 0; i < 8; ++i) e[i] = csr[min(p + i, lim)];
        float w[8];
        #pragma unroll
        for (int i = 0; i < 8; ++i)
            w[i] = (p + i < p1) ? __int_as_float((int)(e[i] >> 32)) : 0.f;
        half8 v[8];
        #pragma unroll
        for (int i = 0; i < 8; ++i)
            v[i] = *(const half8*)&tc[(size_t)(int)e[i] * 32 + c8];
        #pragma unroll
        for (int i = 0; i < 8; ++i) {
            #pragma unroll
            for (int k = 0; k < 8; ++k) acc[k] += w[i] * (float)v[i][k];
        }
    }

    int cbase = chunk * 32 + c8;
    float4 b0 = *(const float4*)&bias[cbase];
    float4 b1 = *(const float4*)&bias[cbase + 4];
    float bb[8] = {b0.x, b0.y, b0.z, b0.w, b1.x, b1.y, b1.z, b1.w};
    unsigned st[8];
    #pragma unroll
    for (int k = 0; k < 8; ++k) st[k] = packsplit(fmaxf(acc[k] + bb[k], 0.f));

    size_t n16 = (size_t)n * 16;
    int hc = chunk * 2 + (lane4 >> 1);
    unsigned* dst = &hp[(size_t)hc * n16 + (size_t)j * 16 + (lane4 & 1) * 8];
    *(uint4*)dst = make_uint4(st[0], st[1], st[2], st[3]);
    *(uint4*)(dst + 4) = make_uint4(st[4], st[5], st[6], st[7]);
}

// ---------------- pooling + classifier (row-major fp32 final activations) ----------------

__global__ __launch_bounds__(256) void pool_kernel(const float* __restrict__ t,
                                                   const float* __restrict__ bfc,
                                                   const int* __restrict__ batch,
                                                   const float* __restrict__ Wlin,
                                                   const float* __restrict__ blin,
                                                   float* __restrict__ out, int n) {
    int g = blockIdx.x;
    int tid = threadIdx.x;
    int lo = 0, hi = n;
    while (lo < hi) { int m = (lo + hi) >> 1; if (batch[m] < g) lo = m + 1; else hi = m; }
    int start = lo;
    lo = start; hi = n;
    while (lo < hi) { int m = (lo + hi) >> 1; if (batch[m] < g + 1) lo = m + 1; else hi = m; }
    int end = lo;

    int lane = tid & 31, sub = tid >> 5;
    int c4 = lane * 4;
    float4 bv = *(const float4*)&bfc[c4];
    float sx = 0.f, sy = 0.f, sz = 0.f, sw = 0.f;
    for (int j = start + sub; j < end; j += 8) {
        float4 v = *(const float4*)&t[(size_t)j * 128 + c4];
        sx += fmaxf(v.x + bv.x, 0.f);
        sy += fmaxf(v.y + bv.y, 0.f);
        sz += fmaxf(v.z + bv.z, 0.f);
        sw += fmaxf(v.w + bv.w, 0.f);
    }
    __shared__ float red[8][128];
    red[sub][c4] = sx; red[sub][c4 + 1] = sy; red[sub][c4 + 2] = sz; red[sub][c4 + 3] = sw;
    __syncthreads();
    __shared__ float pooled[128];
    if (tid < 128) {
        float s = 0.f;
        #pragma unroll
        for (int k = 0; k < 8; ++k) s += red[k][tid];
        float pv = s / fmaxf((float)(end - start), 1.f);
        pooled[tid] = pv;
        out[1280 + g * 128 + tid] = pv;
    }
    __syncthreads();
    if (tid < 10) {
        float a = blin[tid];
        for (int k = 0; k < 128; ++k) a += pooled[k] * Wlin[k * 10 + tid];
        out[g * 10 + tid] = a;
    }
}

// ---------------- launch ----------------

extern "C" void kernel_launch(void* const* d_in, const int* in_sizes, int n_in,
                              void* d_out, int out_size, void* d_ws, size_t ws_size,
                              hipStream_t stream) {
    const float* x     = (const float*)d_in[0];
    const int*   ei    = (const int*)d_in[1];
    const int*   batch = (const int*)d_in[2];
    const float* Wl[6] = {(const float*)d_in[3], (const float*)d_in[5], (const float*)d_in[7],
                          (const float*)d_in[9], (const float*)d_in[11], (const float*)d_in[13]};
    const float* bl[6] = {(const float*)d_in[4], (const float*)d_in[6], (const float*)d_in[8],
                          (const float*)d_in[10], (const float*)d_in[12], (const float*)d_in[14]};
    const float* Wlin = (const float*)d_in[15];
    const float* blin = (const float*)d_in[16];

    const int N = in_sizes[2];        // 50000
    const int E = in_sizes[1] / 2;    // 600000
    (void)n_in; (void)out_size; (void)ws_size;

    char* p = (char*)d_ws;
    auto carve = [&](size_t bytes) { void* r = (void*)p; p += (bytes + 255) & ~(size_t)255; return r; };
    // th (fp16 gather operand, layers 0-4) and tf (fp32 final activations) share a region.
    void*           treg   = carve((size_t)N * 128 * 4);
    _Float16*       th     = (_Float16*)treg;
    float*          tf     = (float*)treg;
    unsigned*       hp     = (unsigned*)carve((size_t)N * 128 * 4);   // packed agg output (chunk8)
    int*            degx   = (int*)carve((size_t)(N + 128) * 4);      // degi | hist(64) | hcur(64)
    int*            degi   = degx;
    int*            hist   = degx + N;
    int*            hcur   = degx + N + 64;
    float*          dinv   = (float*)carve((size_t)N * 4);
    int*            rp     = (int*)carve((size_t)(N + 1) * 4);
    int*            cursor = (int*)carve((size_t)N * 4);
    int*            order  = (int*)carve((size_t)N * 4);
    long long*      csr    = (long long*)carve((size_t)(E + N) * 8);
    int*            bsum   = (int*)carve(256 * 4);
    unsigned short* wth    = (unsigned short*)carve(6 * 16384 * 2);
    unsigned short* wtl    = (unsigned short*)carve(6 * 16384 * 2);

    int gN = (N + 255) / 256;
    hipMemsetAsync(degx, 0, (size_t)(N + 128) * 4, stream);
    count_kernel<<<(E + 255) / 256, 256, 0, stream>>>(ei, degi, E);
    scan_bsum_kernel<<<gN, 256, 0, stream>>>(degi, dinv, bsum, hist, N);
    bucket_scan_kernel<<<1, 64, 0, stream>>>(hist, hcur);
    scan_emit_kernel<<<gN, 256, 0, stream>>>(degi, bsum, rp, cursor, N, gN);
    order_kernel<<<gN, 256, 0, stream>>>(degi, hcur, order, N);
    fill_kernel<<<(E + 255) / 256, 256, 0, stream>>>(ei, dinv, cursor, csr, E);
    packw_kernel<<<dim3(64, 6), 256, 0, stream>>>(Wl[0], Wl[1], Wl[2], Wl[3], Wl[4], Wl[5],
                                                  wth, wtl);

    int NH = (N + 1) / 2;
    int gGemm = (N + 127) / 128;
    int gAgg  = 8 * ((NH + 63) / 64);   // s = bid%8: chunk = s&3, node-half = s>>2
    gemm0_kernel<<<gGemm, 512, 0, stream>>>(x, wth, wtl, th, N);
    agg_kernel<<<gAgg, 256, 0, stream>>>(th, bl[0], rp, csr, dinv, order, hp, N, NH);
    for (int l = 1; l < 5; ++l) {
        gemm_kernel<<<gGemm, 512, 0, stream>>>(hp, wth + l * 16384, wtl + l * 16384,
                                               (void*)th, N, 0);
        agg_kernel<<<gAgg, 256, 0, stream>>>(th, bl[l], rp, csr, dinv, order, hp, N, NH);
    }
    gemm_kernel<<<gGemm, 512, 0, stream>>>(hp, wth + 5 * 16384, wtl + 5 * 16384,
                                           (void*)tf, N, 1);
    pool_kernel<<<128, 256, 0, stream>>>(tf, bl[5], batch, Wlin, blin, (float*)d_out, N);
}

// Round 8
// 402.630 us; speedup vs baseline: 1.5158x; 1.5158x over previous
//
#include <hip/hip_runtime.h>

typedef __attribute__((ext_vector_type(8))) short short8;
typedef __attribute__((ext_vector_type(4))) float floatx4;
typedef __attribute__((ext_vector_type(4))) unsigned uintx4;
typedef __attribute__((ext_vector_type(8))) _Float16 half8;

// ---- bf16 split helpers (round-to-nearest-even) ----
static __device__ __forceinline__ unsigned short f2bf(float f) {
    unsigned u = __float_as_uint(f);
    u += 0x7fff + ((u >> 16) & 1);
    return (unsigned short)(u >> 16);
}
static __device__ __forceinline__ float bf2f(unsigned short h) {
    return __uint_as_float((unsigned)h << 16);
}
static __device__ __forceinline__ unsigned packsplit(float f) {
    unsigned short hi = f2bf(f);
    unsigned short lo = f2bf(f - bf2f(hi));
    return ((unsigned)hi << 16) | lo;
}

// ---------------- CSR build (degi memset to 0 by host-side hipMemsetAsync) ----------------
// WEIGHT-FREE CSR: w(r,c) = dinv[r]*dinv[c] is factored out — dinv[r] folded into the
// gemm epilogue (t' = dinv*t stored fp16), dinv[c] applied once in the agg epilogue.
// csr entry = 4-byte source index only (was 8B index+weight): agg reads csr once per
// chunk (4x per dispatch), so this halves the dominant stream (19.2 -> 9.6 MB/dispatch).
// Self-loops not in csr (term = t'[c], added directly).

__global__ void count_kernel(const int* __restrict__ ei, int* degi, int E) {
    int e = blockIdx.x * 256 + threadIdx.x;
    if (e < E) atomicAdd(&degi[ei[E + e]], 1);   // col = dest
}

__global__ __launch_bounds__(256) void scan_bsum_kernel(const int* __restrict__ degi,
                                                        float* __restrict__ dinv,
                                                        int* bsum, int n) {
    int tid = threadIdx.x;
    int i = blockIdx.x * 256 + tid;
    int d = (i < n) ? degi[i] : 0;
    if (i < n) dinv[i] = rsqrtf((float)(d + 1));  // +1 self-loop for normalization
    int v = d;                                    // offsets count only real edges
    #pragma unroll
    for (int off = 32; off > 0; off >>= 1) v += __shfl_down(v, off);
    __shared__ int ws[4];
    if ((tid & 63) == 0) ws[tid >> 6] = v;
    __syncthreads();
    if (tid == 0) bsum[blockIdx.x] = ws[0] + ws[1] + ws[2] + ws[3];
}

__global__ __launch_bounds__(256) void scan_emit_kernel(const int* __restrict__ degi,
                                                        const int* __restrict__ bsum,
                                                        int* rp, int* cursor, int n, int nb) {
    int tid = threadIdx.x;
    int bid = blockIdx.x;
    int contrib = 0;
    for (int t = tid; t < bid; t += 256) contrib += bsum[t];
    int cr = contrib;
    #pragma unroll
    for (int off = 32; off > 0; off >>= 1) cr += __shfl_down(cr, off);
    __shared__ int wr[4];
    __shared__ int s_boff;
    if ((tid & 63) == 0) wr[tid >> 6] = cr;
    __syncthreads();
    if (tid == 0) s_boff = wr[0] + wr[1] + wr[2] + wr[3];
    __syncthreads();

    int i = bid * 256 + tid;
    int v = (i < n) ? degi[i] : 0;
    int lane = tid & 63, wid = tid >> 6;
    int x = v;
    #pragma unroll
    for (int off = 1; off < 64; off <<= 1) {
        int y = __shfl_up(x, off);
        if (lane >= off) x += y;
    }
    __shared__ int ws[4];
    if (lane == 63) ws[wid] = x;
    __syncthreads();
    if (tid == 0) { int a = 0; for (int j = 0; j < 4; ++j) { int t = ws[j]; ws[j] = a; a += t; } }
    __syncthreads();
    int excl = x - v + ws[wid] + s_boff;
    if (i < n) { rp[i] = excl; cursor[i] = excl; }
    if (i == n - 1) rp[n] = excl + v;
}

__global__ void fill_kernel(const int* __restrict__ ei, int* cursor,
                            int* __restrict__ csr, int E) {
    int e = blockIdx.x * 256 + threadIdx.x;
    if (e >= E) return;
    int r = ei[e], c = ei[E + e];
    int pos = atomicAdd(&cursor[c], 1);
    csr[pos] = r;
}

// ---------------- weight packing: W[k][n] -> Wt_hi[n][k], Wt_lo[n][k] ----------------

__global__ void packw_kernel(const float* w0, const float* w1, const float* w2,
                             const float* w3, const float* w4, const float* w5,
                             unsigned short* __restrict__ hi, unsigned short* __restrict__ lo) {
    int l = blockIdx.y;
    const float* W = (l == 0) ? w0 : (l == 1) ? w1 : (l == 2) ? w2
                   : (l == 3) ? w3 : (l == 4) ? w4 : w5;
    int idx = blockIdx.x * 256 + threadIdx.x;
    int k = idx >> 7, nn = idx & 127;
    float v = W[k * 128 + nn];
    unsigned short h = f2bf(v);
    unsigned short ls = f2bf(v - bf2f(h));
    hi[l * 16384 + nn * 128 + k] = h;
    lo[l * 16384 + nn * 128 + k] = ls;
}

// ---------------- split-bf16 MFMA GEMM core ----------------
// A-input: hp packed split-bf16, chunked [8][node][16] (chunk = col/16).
// outf=0: store t'[row] = dinv[row] * acc as _Float16 chunked [4][node][32]
//         (dinv[r] half of the GCN edge weight, folded into the epilogue).
// outf=1: fp32 row-major [node][128], UNSCALED (final layer, feeds pool).
// 3-MFMA split product (al*wl dropped, absmax-neutral per R5/R6).

#define WLDS_STRIDE 260

static __device__ __forceinline__ void stage_w(const unsigned short* __restrict__ Wth,
                                               const unsigned short* __restrict__ Wtl,
                                               unsigned short* Wlds, int tid) {
    #pragma unroll
    for (int it = 0; it < 8; ++it) {
        int c = it * 512 + tid;
        int row = c >> 5, piece = c & 31;
        const unsigned short* src = (piece < 16)
            ? (Wth + (size_t)row * 128 + piece * 8)
            : (Wtl + (size_t)row * 128 + (piece - 16) * 8);
        int dst = row * WLDS_STRIDE + ((piece < 16) ? piece * 8 : 128 + (piece - 16) * 8);
        *(short8*)&Wlds[dst] = *(const short8*)src;
    }
}

static __device__ __forceinline__ void unpack_u(uintx4 u0, uintx4 u1, short8& ah, short8& al) {
    #pragma unroll
    for (int j = 0; j < 4; ++j) {
        ah[j]     = (short)(u0[j] >> 16); al[j]     = (short)(u0[j] & 0xffff);
        ah[4 + j] = (short)(u1[j] >> 16); al[4 + j] = (short)(u1[j] & 0xffff);
    }
}

__global__ __launch_bounds__(512, 4) void gemm_kernel(const unsigned* __restrict__ Ap,
                                                      const unsigned short* __restrict__ Wth,
                                                      const unsigned short* __restrict__ Wtl,
                                                      const float* __restrict__ dinv,
                                                      void* __restrict__ C, int n, int outf) {
    __shared__ unsigned short Wlds[128 * WLDS_STRIDE];
    int tid = threadIdx.x;
    int wave = tid >> 6, lane = tid & 63;
    int m = lane & 15, quad = lane >> 4;
    int row0 = blockIdx.x * 128 + wave * 16;
    int arow = row0 + m; if (arow > n - 1) arow = n - 1;
    size_t n16 = (size_t)n * 16;
    size_t n32 = (size_t)n * 32;
    const unsigned* abase = Ap + (size_t)arow * 16 + (quad & 1) * 8;
    int chalf = quad >> 1;

    // prefetch ALL kc A-fragments before W staging
    uintx4 pa0[4], pa1[4];
    #pragma unroll
    for (int kc = 0; kc < 4; ++kc) {
        const unsigned* ap = abase + (size_t)(2 * kc + chalf) * n16;
        pa0[kc] = *(const uintx4*)ap;
        pa1[kc] = *(const uintx4*)(ap + 4);
    }

    stage_w(Wth, Wtl, Wlds, tid);

    floatx4 acc[8];
    #pragma unroll
    for (int ct = 0; ct < 8; ++ct) acc[ct] = (floatx4){0.f, 0.f, 0.f, 0.f};
    __syncthreads();

    #pragma unroll
    for (int kc = 0; kc < 4; ++kc) {
        short8 ah, al;
        unpack_u(pa0[kc], pa1[kc], ah, al);
        #pragma unroll
        for (int ct = 0; ct < 8; ++ct) {
            int base = (ct * 16 + m) * WLDS_STRIDE + kc * 32 + quad * 8;
            short8 wh = *(const short8*)&Wlds[base];
            short8 wl = *(const short8*)&Wlds[base + 128];
            acc[ct] = __builtin_amdgcn_mfma_f32_16x16x32_bf16(ah, wl, acc[ct], 0, 0, 0);
            acc[ct] = __builtin_amdgcn_mfma_f32_16x16x32_bf16(al, wh, acc[ct], 0, 0, 0);
            acc[ct] = __builtin_amdgcn_mfma_f32_16x16x32_bf16(ah, wh, acc[ct], 0, 0, 0);
        }
    }

    float dv[4];
    #pragma unroll
    for (int r = 0; r < 4; ++r) dv[r] = dinv[min(row0 + quad * 4 + r, n - 1)];

    #pragma unroll
    for (int ct = 0; ct < 8; ++ct) {
        #pragma unroll
        for (int r = 0; r < 4; ++r) {
            int row = row0 + quad * 4 + r;
            if (row < n) {
                if (outf) {
                    ((float*)C)[(size_t)row * 128 + ct * 16 + m] = acc[ct][r];
                } else {
                    ((_Float16*)C)[(size_t)(ct >> 1) * n32 + (size_t)row * 32
                                   + (ct & 1) * 16 + m] = (_Float16)(acc[ct][r] * dv[r]);
                }
            }
        }
    }
}

// layer-0 variant: reads fp32 x (row-major input) directly; dinv-scaled fp16-chunked out
__global__ __launch_bounds__(512, 4) void gemm0_kernel(const float* __restrict__ X,
                                                       const unsigned short* __restrict__ Wth,
                                                       const unsigned short* __restrict__ Wtl,
                                                       const float* __restrict__ dinv,
                                                       _Float16* __restrict__ C, int n) {
    __shared__ unsigned short Wlds[128 * WLDS_STRIDE];
    int tid = threadIdx.x;
    int wave = tid >> 6, lane = tid & 63;
    int m = lane & 15, quad = lane >> 4;
    int row0 = blockIdx.x * 128 + wave * 16;
    int arow = row0 + m; if (arow > n - 1) arow = n - 1;
    size_t n32 = (size_t)n * 32;
    const float* aptr = X + (size_t)arow * 128 + quad * 8;

    floatx4 pf0[4], pf1[4];
    #pragma unroll
    for (int kc = 0; kc < 4; ++kc) {
        pf0[kc] = *(const floatx4*)(aptr + kc * 32);
        pf1[kc] = *(const floatx4*)(aptr + kc * 32 + 4);
    }

    stage_w(Wth, Wtl, Wlds, tid);

    floatx4 acc[8];
    #pragma unroll
    for (int ct = 0; ct < 8; ++ct) acc[ct] = (floatx4){0.f, 0.f, 0.f, 0.f};
    __syncthreads();

    #pragma unroll
    for (int kc = 0; kc < 4; ++kc) {
        short8 ah, al;
        #pragma unroll
        for (int j = 0; j < 8; ++j) {
            float fv = (j < 4) ? pf0[kc][j] : pf1[kc][j - 4];
            unsigned short h = f2bf(fv);
            ah[j] = (short)h;
            al[j] = (short)f2bf(fv - bf2f(h));
        }
        #pragma unroll
        for (int ct = 0; ct < 8; ++ct) {
            int base = (ct * 16 + m) * WLDS_STRIDE + kc * 32 + quad * 8;
            short8 wh = *(const short8*)&Wlds[base];
            short8 wl = *(const short8*)&Wlds[base + 128];
            acc[ct] = __builtin_amdgcn_mfma_f32_16x16x32_bf16(ah, wl, acc[ct], 0, 0, 0);
            acc[ct] = __builtin_amdgcn_mfma_f32_16x16x32_bf16(al, wh, acc[ct], 0, 0, 0);
            acc[ct] = __builtin_amdgcn_mfma_f32_16x16x32_bf16(ah, wh, acc[ct], 0, 0, 0);
        }
    }

    float dv[4];
    #pragma unroll
    for (int r = 0; r < 4; ++r) dv[r] = dinv[min(row0 + quad * 4 + r, n - 1)];

    #pragma unroll
    for (int ct = 0; ct < 8; ++ct) {
        #pragma unroll
        for (int r = 0; r < 4; ++r) {
            int row = row0 + quad * 4 + r;
            if (row < n)
                C[(size_t)(ct >> 1) * n32 + (size_t)row * 32 + (ct & 1) * 16 + m] =
                    (_Float16)(acc[ct][r] * dv[r]);
        }
    }
}

// ---------------- aggregation: fp16 gather, weight-free csr, XCD-pinned chunks ----------
// t' layout: [4][node][32] fp16 (dinv-prescaled); blockIdx%8 = s: chunk=s&3, half=s>>2.
// out[c] = relu( dinv[c] * (t'[c] + sum_{r in N(c)} t'[r]) + bias ).
// Main loop: pure adds over 8-packed 4B indices; one masked tail pack.

__global__ __launch_bounds__(256) void agg_kernel(const _Float16* __restrict__ t,
                                                  const float* __restrict__ bias,
                                                  const int* __restrict__ rp,
                                                  const int* __restrict__ csr,
                                                  const float* __restrict__ dinv,
                                                  unsigned* __restrict__ hp, int n, int nh) {
    int s = blockIdx.x & 7;
    int chunk = s & 3;
    int half = s >> 2;
    int nb = blockIdx.x >> 3;
    int group = threadIdx.x >> 2;          // 64 nodes per block
    int lane4 = threadIdx.x & 3;
    int j = half * nh + nb * 64 + group;
    int jend = half ? n : nh;
    if (j >= jend) return;
    size_t n32 = (size_t)n * 32;
    const _Float16* tc = t + (size_t)chunk * n32;
    int c8 = lane4 * 8;                    // col offset within the 32-col chunk
    int p0 = rp[j], p1 = rp[j + 1];

    // self-loop term = t'[j] (weight folded): coalesced read, issued first
    float dj = dinv[j];
    half8 vs = *(const half8*)&tc[(size_t)j * 32 + c8];

    float acc[8];
    #pragma unroll
    for (int k = 0; k < 8; ++k) acc[k] = (float)vs[k];

    int p = p0;
    for (; p + 8 <= p1; p += 8) {
        int e[8];
        #pragma unroll
        for (int i = 0; i < 8; ++i) e[i] = csr[p + i];
        half8 v[8];
        #pragma unroll
        for (int i = 0; i < 8; ++i)
            v[i] = *(const half8*)&tc[(size_t)e[i] * 32 + c8];
        #pragma unroll
        for (int i = 0; i < 8; ++i) {
            #pragma unroll
            for (int k = 0; k < 8; ++k) acc[k] += (float)v[i][k];
        }
    }
    if (p < p1) {
        int lim = p1 - 1;
        int e[8];
        #pragma unroll
        for (int i = 0; i < 8; ++i) e[i] = csr[min(p + i, lim)];
        float msk[8];
        #pragma unroll
        for (int i = 0; i < 8; ++i) msk[i] = (p + i < p1) ? 1.f : 0.f;
        half8 v[8];
        #pragma unroll
        for (int i = 0; i < 8; ++i)
            v[i] = *(const half8*)&tc[(size_t)e[i] * 32 + c8];
        #pragma unroll
        for (int i = 0; i < 8; ++i) {
            #pragma unroll
            for (int k = 0; k < 8; ++k) acc[k] += msk[i] * (float)v[i][k];
        }
    }

    int cbase = chunk * 32 + c8;
    float4 b0 = *(const float4*)&bias[cbase];
    float4 b1 = *(const float4*)&bias[cbase + 4];
    float bb[8] = {b0.x, b0.y, b0.z, b0.w, b1.x, b1.y, b1.z, b1.w};
    unsigned st[8];
    #pragma unroll
    for (int k = 0; k < 8; ++k) st[k] = packsplit(fmaxf(fmaf(dj, acc[k], bb[k]), 0.f));

    size_t n16 = (size_t)n * 16;
    int hc = chunk * 2 + (lane4 >> 1);
    unsigned* dst = &hp[(size_t)hc * n16 + (size_t)j * 16 + (lane4 & 1) * 8];
    *(uint4*)dst = make_uint4(st[0], st[1], st[2], st[3]);
    *(uint4*)(dst + 4) = make_uint4(st[4], st[5], st[6], st[7]);
}

// ---------------- pooling + classifier (row-major fp32 final activations) ----------------

__global__ __launch_bounds__(256) void pool_kernel(const float* __restrict__ t,
                                                   const float* __restrict__ bfc,
                                                   const int* __restrict__ batch,
                                                   const float* __restrict__ Wlin,
                                                   const float* __restrict__ blin,
                                                   float* __restrict__ out, int n) {
    int g = blockIdx.x;
    int tid = threadIdx.x;
    int lo = 0, hi = n;
    while (lo < hi) { int m = (lo + hi) >> 1; if (batch[m] < g) lo = m + 1; else hi = m; }
    int start = lo;
    lo = start; hi = n;
    while (lo < hi) { int m = (lo + hi) >> 1; if (batch[m] < g + 1) lo = m + 1; else hi = m; }
    int end = lo;

    int lane = tid & 31, sub = tid >> 5;
    int c4 = lane * 4;
    float4 bv = *(const float4*)&bfc[c4];
    float sx = 0.f, sy = 0.f, sz = 0.f, sw = 0.f;
    for (int j = start + sub; j < end; j += 8) {
        float4 v = *(const float4*)&t[(size_t)j * 128 + c4];
        sx += fmaxf(v.x + bv.x, 0.f);
        sy += fmaxf(v.y + bv.y, 0.f);
        sz += fmaxf(v.z + bv.z, 0.f);
        sw += fmaxf(v.w + bv.w, 0.f);
    }
    __shared__ float red[8][128];
    red[sub][c4] = sx; red[sub][c4 + 1] = sy; red[sub][c4 + 2] = sz; red[sub][c4 + 3] = sw;
    __syncthreads();
    __shared__ float pooled[128];
    if (tid < 128) {
        float s = 0.f;
        #pragma unroll
        for (int k = 0; k < 8; ++k) s += red[k][tid];
        float pv = s / fmaxf((float)(end - start), 1.f);
        pooled[tid] = pv;
        out[1280 + g * 128 + tid] = pv;
    }
    __syncthreads();
    if (tid < 10) {
        float a = blin[tid];
        for (int k = 0; k < 128; ++k) a += pooled[k] * Wlin[k * 10 + tid];
        out[g * 10 + tid] = a;
    }
}

// ---------------- launch ----------------

extern "C" void kernel_launch(void* const* d_in, const int* in_sizes, int n_in,
                              void* d_out, int out_size, void* d_ws, size_t ws_size,
                              hipStream_t stream) {
    const float* x     = (const float*)d_in[0];
    const int*   ei    = (const int*)d_in[1];
    const int*   batch = (const int*)d_in[2];
    const float* Wl[6] = {(const float*)d_in[3], (const float*)d_in[5], (const float*)d_in[7],
                          (const float*)d_in[9], (const float*)d_in[11], (const float*)d_in[13]};
    const float* bl[6] = {(const float*)d_in[4], (const float*)d_in[6], (const float*)d_in[8],
                          (const float*)d_in[10], (const float*)d_in[12], (const float*)d_in[14]};
    const float* Wlin = (const float*)d_in[15];
    const float* blin = (const float*)d_in[16];

    const int N = in_sizes[2];        // 50000
    const int E = in_sizes[1] / 2;    // 600000
    (void)n_in; (void)out_size; (void)ws_size;

    char* p = (char*)d_ws;
    auto carve = [&](size_t bytes) { void* r = (void*)p; p += (bytes + 255) & ~(size_t)255; return r; };
    // th (fp16 dinv-scaled gather operand) and tf (fp32 final activations) share a region.
    void*           treg   = carve((size_t)N * 128 * 4);
    _Float16*       th     = (_Float16*)treg;
    float*          tf     = (float*)treg;
    unsigned*       hp     = (unsigned*)carve((size_t)N * 128 * 4);   // packed agg output (chunk8)
    int*            degi   = (int*)carve((size_t)N * 4);
    float*          dinv   = (float*)carve((size_t)N * 4);
    int*            rp     = (int*)carve((size_t)(N + 1) * 4);
    int*            cursor = (int*)carve((size_t)N * 4);
    int*            csr    = (int*)carve((size_t)E * 4);              // 4B source index only
    int*            bsum   = (int*)carve(256 * 4);
    unsigned short* wth    = (unsigned short*)carve(6 * 16384 * 2);
    unsigned short* wtl    = (unsigned short*)carve(6 * 16384 * 2);

    int gN = (N + 255) / 256;
    hipMemsetAsync(degi, 0, (size_t)N * 4, stream);
    count_kernel<<<(E + 255) / 256, 256, 0, stream>>>(ei, degi, E);
    scan_bsum_kernel<<<gN, 256, 0, stream>>>(degi, dinv, bsum, N);
    scan_emit_kernel<<<gN, 256, 0, stream>>>(degi, bsum, rp, cursor, N, gN);
    fill_kernel<<<(E + 255) / 256, 256, 0, stream>>>(ei, cursor, csr, E);
    packw_kernel<<<dim3(64, 6), 256, 0, stream>>>(Wl[0], Wl[1], Wl[2], Wl[3], Wl[4], Wl[5],
                                                  wth, wtl);

    int NH = (N + 1) / 2;
    int gGemm = (N + 127) / 128;
    int gAgg  = 8 * ((NH + 63) / 64);   // s = bid%8: chunk = s&3, node-half = s>>2
    gemm0_kernel<<<gGemm, 512, 0, stream>>>(x, wth, wtl, dinv, th, N);
    agg_kernel<<<gAgg, 256, 0, stream>>>(th, bl[0], rp, csr, dinv, hp, N, NH);
    for (int l = 1; l < 5; ++l) {
        gemm_kernel<<<gGemm, 512, 0, stream>>>(hp, wth + l * 16384, wtl + l * 16384,
                                               dinv, (void*)th, N, 0);
        agg_kernel<<<gAgg, 256, 0, stream>>>(th, bl[l], rp, csr, dinv, hp, N, NH);
    }
    gemm_kernel<<<gGemm, 512, 0, stream>>>(hp, wth + 5 * 16384, wtl + 5 * 16384,
                                           dinv, (void*)tf, N, 1);
    pool_kernel<<<128, 256, 0, stream>>>(tf, bl[5], batch, Wlin, blin, (float*)d_out, N);
}

// Round 9
// 395.970 us; speedup vs baseline: 1.5413x; 1.0168x over previous
//
#include <hip/hip_runtime.h>

typedef __attribute__((ext_vector_type(8))) short short8;
typedef __attribute__((ext_vector_type(4))) float floatx4;
typedef __attribute__((ext_vector_type(4))) unsigned uintx4;
typedef __attribute__((ext_vector_type(8))) _Float16 half8;

// ---- bf16 split helpers (round-to-nearest-even) ----
static __device__ __forceinline__ unsigned short f2bf(float f) {
    unsigned u = __float_as_uint(f);
    u += 0x7fff + ((u >> 16) & 1);
    return (unsigned short)(u >> 16);
}
static __device__ __forceinline__ float bf2f(unsigned short h) {
    return __uint_as_float((unsigned)h << 16);
}

// ---------------- CSR build (degi memset to 0 by host-side hipMemsetAsync) ----------------
// Weight-free CSR (R8): w(r,c)=dinv[r]*dinv[c] factored into gemm epilogue (dinv[r]) and
// agg epilogue (dinv[c]). csr entry = 4-byte source index. Self-loops not stored.

__global__ void count_kernel(const int* __restrict__ ei, int* degi, int E) {
    int e = blockIdx.x * 256 + threadIdx.x;
    if (e < E) atomicAdd(&degi[ei[E + e]], 1);   // col = dest
}

__global__ __launch_bounds__(256) void scan_bsum_kernel(const int* __restrict__ degi,
                                                        float* __restrict__ dinv,
                                                        int* bsum, int n) {
    int tid = threadIdx.x;
    int i = blockIdx.x * 256 + tid;
    int d = (i < n) ? degi[i] : 0;
    if (i < n) dinv[i] = rsqrtf((float)(d + 1));  // +1 self-loop for normalization
    int v = d;                                    // offsets count only real edges
    #pragma unroll
    for (int off = 32; off > 0; off >>= 1) v += __shfl_down(v, off);
    __shared__ int ws[4];
    if ((tid & 63) == 0) ws[tid >> 6] = v;
    __syncthreads();
    if (tid == 0) bsum[blockIdx.x] = ws[0] + ws[1] + ws[2] + ws[3];
}

__global__ __launch_bounds__(256) void scan_emit_kernel(const int* __restrict__ degi,
                                                        const int* __restrict__ bsum,
                                                        int* rp, int* cursor, int n, int nb) {
    int tid = threadIdx.x;
    int bid = blockIdx.x;
    int contrib = 0;
    for (int t = tid; t < bid; t += 256) contrib += bsum[t];
    int cr = contrib;
    #pragma unroll
    for (int off = 32; off > 0; off >>= 1) cr += __shfl_down(cr, off);
    __shared__ int wr[4];
    __shared__ int s_boff;
    if ((tid & 63) == 0) wr[tid >> 6] = cr;
    __syncthreads();
    if (tid == 0) s_boff = wr[0] + wr[1] + wr[2] + wr[3];
    __syncthreads();

    int i = bid * 256 + tid;
    int v = (i < n) ? degi[i] : 0;
    int lane = tid & 63, wid = tid >> 6;
    int x = v;
    #pragma unroll
    for (int off = 1; off < 64; off <<= 1) {
        int y = __shfl_up(x, off);
        if (lane >= off) x += y;
    }
    __shared__ int ws[4];
    if (lane == 63) ws[wid] = x;
    __syncthreads();
    if (tid == 0) { int a = 0; for (int j = 0; j < 4; ++j) { int t = ws[j]; ws[j] = a; a += t; } }
    __syncthreads();
    int excl = x - v + ws[wid] + s_boff;
    if (i < n) { rp[i] = excl; cursor[i] = excl; }
    if (i == n - 1) rp[n] = excl + v;
}

__global__ void fill_kernel(const int* __restrict__ ei, int* cursor,
                            int* __restrict__ csr, int E) {
    int e = blockIdx.x * 256 + threadIdx.x;
    if (e >= E) return;
    int r = ei[e], c = ei[E + e];
    int pos = atomicAdd(&cursor[c], 1);
    csr[pos] = r;
}

// ---------------- weight packing: W[k][n] -> Wt_hi[n][k], Wt_lo[n][k] ----------------

__global__ void packw_kernel(const float* w0, const float* w1, const float* w2,
                             const float* w3, const float* w4, const float* w5,
                             unsigned short* __restrict__ hi, unsigned short* __restrict__ lo) {
    int l = blockIdx.y;
    const float* W = (l == 0) ? w0 : (l == 1) ? w1 : (l == 2) ? w2
                   : (l == 3) ? w3 : (l == 4) ? w4 : w5;
    int idx = blockIdx.x * 256 + threadIdx.x;
    int k = idx >> 7, nn = idx & 127;
    float v = W[k * 128 + nn];
    unsigned short h = f2bf(v);
    unsigned short ls = f2bf(v - bf2f(h));
    hi[l * 16384 + nn * 128 + k] = h;
    lo[l * 16384 + nn * 128 + k] = ls;
}

// ---------------- split-bf16 MFMA GEMM core ----------------
// A-input: fp16 chunk4 [4][node][32] (the ONE unified activation format).
// Exact in-register truncation split: fp16 value = ah(bf16) + al(bf16) LOSSLESSLY
// (fp16 mantissa 11 bits; hi = top 16 fp32 bits, residual has <=3 significant bits).
// outf=0: store t'[row] = dinv[row]*acc as fp16 chunk4 (gather operand).
// outf=1: fp32 row-major (final layer, feeds pool).
// 3-MFMA split product (ah*wh + al*wh + ah*wl; al*wl ~2^-19, dropped).

#define WLDS_STRIDE 260

static __device__ __forceinline__ void stage_w(const unsigned short* __restrict__ Wth,
                                               const unsigned short* __restrict__ Wtl,
                                               unsigned short* Wlds, int tid) {
    #pragma unroll
    for (int it = 0; it < 8; ++it) {
        int c = it * 512 + tid;
        int row = c >> 5, piece = c & 31;
        const unsigned short* src = (piece < 16)
            ? (Wth + (size_t)row * 128 + piece * 8)
            : (Wtl + (size_t)row * 128 + (piece - 16) * 8);
        int dst = row * WLDS_STRIDE + ((piece < 16) ? piece * 8 : 128 + (piece - 16) * 8);
        *(short8*)&Wlds[dst] = *(const short8*)src;
    }
}

// exact split of an fp16-origin fp32 value into bf16 hi + bf16 lo (truncation, lossless)
static __device__ __forceinline__ void split_h8(half8 a, short8& ah, short8& al) {
    #pragma unroll
    for (int j = 0; j < 8; ++j) {
        float fv = (float)a[j];
        unsigned u = __float_as_uint(fv);
        float lo = fv - __uint_as_float(u & 0xFFFF0000u);
        ah[j] = (short)(u >> 16);
        al[j] = (short)(__float_as_uint(lo) >> 16);
    }
}

__global__ __launch_bounds__(512, 4) void gemm_kernel(const _Float16* __restrict__ A,
                                                      const unsigned short* __restrict__ Wth,
                                                      const unsigned short* __restrict__ Wtl,
                                                      const float* __restrict__ dinv,
                                                      void* __restrict__ C, int n, int outf) {
    __shared__ unsigned short Wlds[128 * WLDS_STRIDE];
    int tid = threadIdx.x;
    int wave = tid >> 6, lane = tid & 63;
    int m = lane & 15, quad = lane >> 4;
    int row0 = blockIdx.x * 128 + wave * 16;
    int arow = row0 + m; if (arow > n - 1) arow = n - 1;
    size_t n32 = (size_t)n * 32;
    const _Float16* abase = A + (size_t)arow * 32 + quad * 8;

    // prefetch ALL kc A-fragments before W staging (chunk kc holds cols [32kc,32kc+32))
    half8 pa[4];
    #pragma unroll
    for (int kc = 0; kc < 4; ++kc) pa[kc] = *(const half8*)(abase + (size_t)kc * n32);

    stage_w(Wth, Wtl, Wlds, tid);

    floatx4 acc[8];
    #pragma unroll
    for (int ct = 0; ct < 8; ++ct) acc[ct] = (floatx4){0.f, 0.f, 0.f, 0.f};
    __syncthreads();

    #pragma unroll
    for (int kc = 0; kc < 4; ++kc) {
        short8 ah, al;
        split_h8(pa[kc], ah, al);
        #pragma unroll
        for (int ct = 0; ct < 8; ++ct) {
            int base = (ct * 16 + m) * WLDS_STRIDE + kc * 32 + quad * 8;
            short8 wh = *(const short8*)&Wlds[base];
            short8 wl = *(const short8*)&Wlds[base + 128];
            acc[ct] = __builtin_amdgcn_mfma_f32_16x16x32_bf16(ah, wl, acc[ct], 0, 0, 0);
            acc[ct] = __builtin_amdgcn_mfma_f32_16x16x32_bf16(al, wh, acc[ct], 0, 0, 0);
            acc[ct] = __builtin_amdgcn_mfma_f32_16x16x32_bf16(ah, wh, acc[ct], 0, 0, 0);
        }
    }

    float dv[4];
    #pragma unroll
    for (int r = 0; r < 4; ++r) dv[r] = dinv[min(row0 + quad * 4 + r, n - 1)];

    #pragma unroll
    for (int ct = 0; ct < 8; ++ct) {
        #pragma unroll
        for (int r = 0; r < 4; ++r) {
            int row = row0 + quad * 4 + r;
            if (row < n) {
                if (outf) {
                    ((float*)C)[(size_t)row * 128 + ct * 16 + m] = acc[ct][r];
                } else {
                    ((_Float16*)C)[(size_t)(ct >> 1) * n32 + (size_t)row * 32
                                   + (ct & 1) * 16 + m] = (_Float16)(acc[ct][r] * dv[r]);
                }
            }
        }
    }
}

// layer-0 variant: reads fp32 x (row-major input) directly; dinv-scaled fp16-chunked out
__global__ __launch_bounds__(512, 4) void gemm0_kernel(const float* __restrict__ X,
                                                       const unsigned short* __restrict__ Wth,
                                                       const unsigned short* __restrict__ Wtl,
                                                       const float* __restrict__ dinv,
                                                       _Float16* __restrict__ C, int n) {
    __shared__ unsigned short Wlds[128 * WLDS_STRIDE];
    int tid = threadIdx.x;
    int wave = tid >> 6, lane = tid & 63;
    int m = lane & 15, quad = lane >> 4;
    int row0 = blockIdx.x * 128 + wave * 16;
    int arow = row0 + m; if (arow > n - 1) arow = n - 1;
    size_t n32 = (size_t)n * 32;
    const float* aptr = X + (size_t)arow * 128 + quad * 8;

    floatx4 pf0[4], pf1[4];
    #pragma unroll
    for (int kc = 0; kc < 4; ++kc) {
        pf0[kc] = *(const floatx4*)(aptr + kc * 32);
        pf1[kc] = *(const floatx4*)(aptr + kc * 32 + 4);
    }

    stage_w(Wth, Wtl, Wlds, tid);

    floatx4 acc[8];
    #pragma unroll
    for (int ct = 0; ct < 8; ++ct) acc[ct] = (floatx4){0.f, 0.f, 0.f, 0.f};
    __syncthreads();

    #pragma unroll
    for (int kc = 0; kc < 4; ++kc) {
        short8 ah, al;
        #pragma unroll
        for (int j = 0; j < 8; ++j) {
            float fv = (j < 4) ? pf0[kc][j] : pf1[kc][j - 4];
            unsigned short h = f2bf(fv);
            ah[j] = (short)h;
            al[j] = (short)f2bf(fv - bf2f(h));
        }
        #pragma unroll
        for (int ct = 0; ct < 8; ++ct) {
            int base = (ct * 16 + m) * WLDS_STRIDE + kc * 32 + quad * 8;
            short8 wh = *(const short8*)&Wlds[base];
            short8 wl = *(const short8*)&Wlds[base + 128];
            acc[ct] = __builtin_amdgcn_mfma_f32_16x16x32_bf16(ah, wl, acc[ct], 0, 0, 0);
            acc[ct] = __builtin_amdgcn_mfma_f32_16x16x32_bf16(al, wh, acc[ct], 0, 0, 0);
            acc[ct] = __builtin_amdgcn_mfma_f32_16x16x32_bf16(ah, wh, acc[ct], 0, 0, 0);
        }
    }

    float dv[4];
    #pragma unroll
    for (int r = 0; r < 4; ++r) dv[r] = dinv[min(row0 + quad * 4 + r, n - 1)];

    #pragma unroll
    for (int ct = 0; ct < 8; ++ct) {
        #pragma unroll
        for (int r = 0; r < 4; ++r) {
            int row = row0 + quad * 4 + r;
            if (row < n)
                C[(size_t)(ct >> 1) * n32 + (size_t)row * 32 + (ct & 1) * 16 + m] =
                    (_Float16)(acc[ct][r] * dv[r]);
        }
    }
}

// ---------------- aggregation: fp16 in, fp16 out, weight-free csr, XCD-pinned ----------
// tA layout: [4][node][32] fp16 (dinv-prescaled). blockIdx%8 = s: chunk=s&3, half=s>>2.
// out h[c] = relu( dinv[c] * (tA[c] + sum_{r in N(c)} tA[r]) + bias ), stored fp16
// in the SAME chunk4 layout (tB) -> next gemm reads it directly. Writes halve vs
// split-bf16 hp (16B vs 32B per thread) and the packsplit VALU epilogue is gone.

__global__ __launch_bounds__(256) void agg_kernel(const _Float16* __restrict__ t,
                                                  const float* __restrict__ bias,
                                                  const int* __restrict__ rp,
                                                  const int* __restrict__ csr,
                                                  const float* __restrict__ dinv,
                                                  _Float16* __restrict__ outp, int n, int nh) {
    int s = blockIdx.x & 7;
    int chunk = s & 3;
    int half = s >> 2;
    int nb = blockIdx.x >> 3;
    int group = threadIdx.x >> 2;          // 64 nodes per block
    int lane4 = threadIdx.x & 3;
    int j = half * nh + nb * 64 + group;
    int jend = half ? n : nh;
    if (j >= jend) return;
    size_t n32 = (size_t)n * 32;
    const _Float16* tc = t + (size_t)chunk * n32;
    int c8 = lane4 * 8;                    // col offset within the 32-col chunk
    int p0 = rp[j], p1 = rp[j + 1];

    // self-loop term = tA[j] (weight folded): coalesced read, issued first
    float dj = dinv[j];
    half8 vs = *(const half8*)&tc[(size_t)j * 32 + c8];

    float acc[8];
    #pragma unroll
    for (int k = 0; k < 8; ++k) acc[k] = (float)vs[k];

    int p = p0;
    for (; p + 8 <= p1; p += 8) {
        int e[8];
        #pragma unroll
        for (int i = 0; i < 8; ++i) e[i] = csr[p + i];
        half8 v[8];
        #pragma unroll
        for (int i = 0; i < 8; ++i)
            v[i] = *(const half8*)&tc[(size_t)e[i] * 32 + c8];
        #pragma unroll
        for (int i = 0; i < 8; ++i) {
            #pragma unroll
            for (int k = 0; k < 8; ++k) acc[k] += (float)v[i][k];
        }
    }
    if (p < p1) {
        int lim = p1 - 1;
        int e[8];
        #pragma unroll
        for (int i = 0; i < 8; ++i) e[i] = csr[min(p + i, lim)];
        float msk[8];
        #pragma unroll
        for (int i = 0; i < 8; ++i) msk[i] = (p + i < p1) ? 1.f : 0.f;
        half8 v[8];
        #pragma unroll
        for (int i = 0; i < 8; ++i)
            v[i] = *(const half8*)&tc[(size_t)e[i] * 32 + c8];
        #pragma unroll
        for (int i = 0; i < 8; ++i) {
            #pragma unroll
            for (int k = 0; k < 8; ++k) acc[k] += msk[i] * (float)v[i][k];
        }
    }

    int cbase = chunk * 32 + c8;
    float4 b0 = *(const float4*)&bias[cbase];
    float4 b1 = *(const float4*)&bias[cbase + 4];
    float bb[8] = {b0.x, b0.y, b0.z, b0.w, b1.x, b1.y, b1.z, b1.w};
    half8 hv;
    #pragma unroll
    for (int k = 0; k < 8; ++k) hv[k] = (_Float16)fmaxf(fmaf(dj, acc[k], bb[k]), 0.f);

    *(half8*)&outp[(size_t)chunk * n32 + (size_t)j * 32 + c8] = hv;
}

// ---------------- pooling + classifier (row-major fp32 final activations) ----------------

__global__ __launch_bounds__(256) void pool_kernel(const float* __restrict__ t,
                                                   const float* __restrict__ bfc,
                                                   const int* __restrict__ batch,
                                                   const float* __restrict__ Wlin,
                                                   const float* __restrict__ blin,
                                                   float* __restrict__ out, int n) {
    int g = blockIdx.x;
    int tid = threadIdx.x;
    int lo = 0, hi = n;
    while (lo < hi) { int m = (lo + hi) >> 1; if (batch[m] < g) lo = m + 1; else hi = m; }
    int start = lo;
    lo = start; hi = n;
    while (lo < hi) { int m = (lo + hi) >> 1; if (batch[m] < g + 1) lo = m + 1; else hi = m; }
    int end = lo;

    int lane = tid & 31, sub = tid >> 5;
    int c4 = lane * 4;
    float4 bv = *(const float4*)&bfc[c4];
    float sx = 0.f, sy = 0.f, sz = 0.f, sw = 0.f;
    for (int j = start + sub; j < end; j += 8) {
        float4 v = *(const float4*)&t[(size_t)j * 128 + c4];
        sx += fmaxf(v.x + bv.x, 0.f);
        sy += fmaxf(v.y + bv.y, 0.f);
        sz += fmaxf(v.z + bv.z, 0.f);
        sw += fmaxf(v.w + bv.w, 0.f);
    }
    __shared__ float red[8][128];
    red[sub][c4] = sx; red[sub][c4 + 1] = sy; red[sub][c4 + 2] = sz; red[sub][c4 + 3] = sw;
    __syncthreads();
    __shared__ float pooled[128];
    if (tid < 128) {
        float s = 0.f;
        #pragma unroll
        for (int k = 0; k < 8; ++k) s += red[k][tid];
        float pv = s / fmaxf((float)(end - start), 1.f);
        pooled[tid] = pv;
        out[1280 + g * 128 + tid] = pv;
    }
    __syncthreads();
    if (tid < 10) {
        float a = blin[tid];
        for (int k = 0; k < 128; ++k) a += pooled[k] * Wlin[k * 10 + tid];
        out[g * 10 + tid] = a;
    }
}

// ---------------- launch ----------------

extern "C" void kernel_launch(void* const* d_in, const int* in_sizes, int n_in,
                              void* d_out, int out_size, void* d_ws, size_t ws_size,
                              hipStream_t stream) {
    const float* x     = (const float*)d_in[0];
    const int*   ei    = (const int*)d_in[1];
    const int*   batch = (const int*)d_in[2];
    const float* Wl[6] = {(const float*)d_in[3], (const float*)d_in[5], (const float*)d_in[7],
                          (const float*)d_in[9], (const float*)d_in[11], (const float*)d_in[13]};
    const float* bl[6] = {(const float*)d_in[4], (const float*)d_in[6], (const float*)d_in[8],
                          (const float*)d_in[10], (const float*)d_in[12], (const float*)d_in[14]};
    const float* Wlin = (const float*)d_in[15];
    const float* blin = (const float*)d_in[16];

    const int N = in_sizes[2];        // 50000
    const int E = in_sizes[1] / 2;    // 600000
    (void)n_in; (void)out_size; (void)ws_size;

    char* p = (char*)d_ws;
    auto carve = [&](size_t bytes) { void* r = (void*)p; p += (bytes + 255) & ~(size_t)255; return r; };
    _Float16*       tA     = (_Float16*)carve((size_t)N * 128 * 2);   // gemm out (dinv-scaled)
    _Float16*       tB     = (_Float16*)carve((size_t)N * 128 * 2);   // agg out (h)
    float*          tf     = (float*)carve((size_t)N * 128 * 4);      // final fp32 activations
    int*            degi   = (int*)carve((size_t)N * 4);
    float*          dinv   = (float*)carve((size_t)N * 4);
    int*            rp     = (int*)carve((size_t)(N + 1) * 4);
    int*            cursor = (int*)carve((size_t)N * 4);
    int*            csr    = (int*)carve((size_t)E * 4);              // 4B source index only
    int*            bsum   = (int*)carve(256 * 4);
    unsigned short* wth    = (unsigned short*)carve(6 * 16384 * 2);
    unsigned short* wtl    = (unsigned short*)carve(6 * 16384 * 2);

    int gN = (N + 255) / 256;
    hipMemsetAsync(degi, 0, (size_t)N * 4, stream);
    count_kernel<<<(E + 255) / 256, 256, 0, stream>>>(ei, degi, E);
    scan_bsum_kernel<<<gN, 256, 0, stream>>>(degi, dinv, bsum, N);
    scan_emit_kernel<<<gN, 256, 0, stream>>>(degi, bsum, rp, cursor, N, gN);
    fill_kernel<<<(E + 255) / 256, 256, 0, stream>>>(ei, cursor, csr, E);
    packw_kernel<<<dim3(64, 6), 256, 0, stream>>>(Wl[0], Wl[1], Wl[2], Wl[3], Wl[4], Wl[5],
                                                  wth, wtl);

    int NH = (N + 1) / 2;
    int gGemm = (N + 127) / 128;
    int gAgg  = 8 * ((NH + 63) / 64);   // s = bid%8: chunk = s&3, node-half = s>>2
    gemm0_kernel<<<gGemm, 512, 0, stream>>>(x, wth, wtl, dinv, tA, N);
    agg_kernel<<<gAgg, 256, 0, stream>>>(tA, bl[0], rp, csr, dinv, tB, N, NH);
    for (int l = 1; l < 5; ++l) {
        gemm_kernel<<<gGemm, 512, 0, stream>>>(tB, wth + l * 16384, wtl + l * 16384,
                                               dinv, (void*)tA, N, 0);
        agg_kernel<<<gAgg, 256, 0, stream>>>(tA, bl[l], rp, csr, dinv, tB, N, NH);
    }
    gemm_kernel<<<gGemm, 512, 0, stream>>>(tB, wth + 5 * 16384, wtl + 5 * 16384,
                                           dinv, (void*)tf, N, 1);
    pool_kernel<<<128, 256, 0, stream>>>(tf, bl[5], batch, Wlin, blin, (float*)d_out, N);
}